// Round 1
// baseline (4936.832 us; speedup 1.0000x reference)
//
#include <hip/hip_runtime.h>
#include <hip/hip_bf16.h>
#include <math.h>

#define S_LEN 1024
#define B_DIM 4
#define EMB 128
#define HID 768
#define LAYERS 4
#define CW 3
#define NHEAD 12
#define HDIM 64
#define T_LEN (S_LEN - 4*CW)   // 1012
#define LN_EPS 1e-5f
#define MROWS (S_LEN*B_DIM)    // 4096

__device__ __forceinline__ float gelu_exact(float x){
    return 0.5f * x * (1.0f + erff(x * 0.70710678118654752f));
}

__device__ __forceinline__ float softplus_f(float x){
    return fmaxf(x, 0.0f) + log1pf(expf(-fabsf(x)));
}

// ---------------- positional encoding table (S, HID) ----------------
__global__ void k_pe(float* __restrict__ pe){
    int idx = blockIdx.x*256 + threadIdx.x;
    if(idx >= S_LEN*HID) return;
    int s = idx / HID, c = idx % HID;
    int i2 = (c >> 1) * 2;
    float freq = expf(-(float)i2 * (logf(10000.0f) / (float)HID));
    float ang = (float)s * freq;
    pe[idx] = (c & 1) ? cosf(ang) : sinf(ang);
}

// ---------------- z = LN(emb_table[seq^T]) ----------------
// row = s*B + b ; token = seq[b*S + s] ; 64 threads, 2 elems each
__global__ void k_embed_ln(const int* __restrict__ seq,
                           const float* __restrict__ emb,
                           const float* __restrict__ g,
                           const float* __restrict__ bta,
                           float* __restrict__ z){
    int row = blockIdx.x;
    int s = row >> 2, b = row & 3;
    int tok = seq[b*S_LEN + s];
    const float* e = emb + (size_t)tok * EMB;
    int lane = threadIdx.x;
    float v0 = e[lane], v1 = e[lane+64];
    float sum = v0+v1, sq = v0*v0+v1*v1;
    #pragma unroll
    for(int off=32; off; off>>=1){ sum += __shfl_xor(sum,off); sq += __shfl_xor(sq,off); }
    float m = sum * (1.0f/128.0f);
    float var = sq*(1.0f/128.0f) - m*m;
    float r = rsqrtf(var + LN_EPS);
    size_t base = (size_t)row*EMB;
    z[base+lane]    = (v0-m)*r*g[lane]    + bta[lane];
    z[base+lane+64] = (v1-m)*r*g[lane+64] + bta[lane+64];
}

// ---------------- tiled f32 GEMM: C[M,N] = A[M,K] * Bw[N,K]^T + bias ----------------
// EPI: 0 = +bias, 1 = gelu(+bias), 2 = gelu(+bias) + pe[row>>2][col]
template<int EPI>
__global__ __launch_bounds__(256) void k_gemm(
    const float* __restrict__ A, const float* __restrict__ Bw,
    const float* __restrict__ bias, float* __restrict__ C,
    int M, int N, int K, const float* __restrict__ pe)
{
    __shared__ float As[16][65];
    __shared__ float Bs[16][65];
    int tid = threadIdx.x;
    int tx = tid & 15, ty = tid >> 4;
    int row0 = blockIdx.y * 64, col0 = blockIdx.x * 64;
    int lr = tid >> 2;           // 0..63 tile row
    int lc = (tid & 3) * 4;      // 0,4,8,12 k-subcol
    float acc[4][4] = {};
    for(int k0 = 0; k0 < K; k0 += 16){
        float4 av = *(const float4*)(A  + (size_t)(row0+lr)*K + k0 + lc);
        float4 bv = *(const float4*)(Bw + (size_t)(col0+lr)*K + k0 + lc);
        As[lc+0][lr]=av.x; As[lc+1][lr]=av.y; As[lc+2][lr]=av.z; As[lc+3][lr]=av.w;
        Bs[lc+0][lr]=bv.x; Bs[lc+1][lr]=bv.y; Bs[lc+2][lr]=bv.z; Bs[lc+3][lr]=bv.w;
        __syncthreads();
        #pragma unroll
        for(int kk=0;kk<16;kk++){
            float af[4], bf[4];
            #pragma unroll
            for(int i=0;i<4;i++) af[i]=As[kk][ty*4+i];
            #pragma unroll
            for(int j=0;j<4;j++) bf[j]=Bs[kk][tx*4+j];
            #pragma unroll
            for(int i=0;i<4;i++)
              #pragma unroll
              for(int j=0;j<4;j++) acc[i][j] = fmaf(af[i],bf[j],acc[i][j]);
        }
        __syncthreads();
    }
    #pragma unroll
    for(int i=0;i<4;i++){
        int row = row0 + ty*4 + i;
        #pragma unroll
        for(int j=0;j<4;j++){
            int col = col0 + tx*4 + j;
            float v = acc[i][j] + bias[col];
            if(EPI==1) v = gelu_exact(v);
            if(EPI==2) v = gelu_exact(v) + pe[(size_t)(row>>2)*HID + col];
            C[(size_t)row*N + col] = v;
        }
    }
}

// ---------------- banded attention ----------------
// qkv layout: row r = s*B+b, 2304 cols: q[h*64+d], k[768+h*64+d], v[1536+h*64+d]
// allowed keys: t = s+g, g in [0,12], g != 6, t < S
__global__ void k_attn(const float* __restrict__ qkv, float* __restrict__ out){
    int bid = blockIdx.x;                 // s*(B*NHEAD) + b*NHEAD + h
    int h = bid % NHEAD;
    int b = (bid / NHEAD) & 3;
    int s = bid / (NHEAD*B_DIM);
    int lane = threadIdx.x;
    const float scale = 0.125f;           // 1/sqrt(64)
    float qd = qkv[((size_t)(s*B_DIM+b)*3*HID) + h*HDIM + lane] * scale;
    float sc[13];
    #pragma unroll
    for(int g=0; g<13; ++g){
        sc[g] = -INFINITY;
        int t = s + g;
        if(g==6 || t >= S_LEN) continue;
        float kd = qkv[((size_t)(t*B_DIM+b)*3*HID) + HID + h*HDIM + lane];
        float p = qd*kd;
        #pragma unroll
        for(int off=32; off; off>>=1) p += __shfl_xor(p, off);
        sc[g] = p;
    }
    float m = sc[0];
    #pragma unroll
    for(int g=1; g<13; ++g) m = fmaxf(m, sc[g]);
    float w[13]; float wsum = 0.f;
    #pragma unroll
    for(int g=0; g<13; ++g){ w[g] = expf(sc[g]-m); wsum += w[g]; }
    float accv = 0.f;
    #pragma unroll
    for(int g=0; g<13; ++g){
        int t = s + g;
        if(g==6 || t >= S_LEN) continue;
        accv += w[g] * qkv[((size_t)(t*B_DIM+b)*3*HID) + 2*HID + h*HDIM + lane];
    }
    out[(size_t)(s*B_DIM+b)*HID + h*HDIM + lane] = accv / wsum;
}

// ---------------- x = LN(x + y) over 768, per row ----------------
__global__ __launch_bounds__(256) void k_add_ln768(
    float* __restrict__ x, const float* __restrict__ y,
    const float* __restrict__ g, const float* __restrict__ bta)
{
    int row = blockIdx.x;
    size_t base = (size_t)row * HID;
    int tid = threadIdx.x;
    float v[3]; float sum=0.f, sq=0.f;
    #pragma unroll
    for(int i=0;i<3;i++){
        int c = tid + i*256;
        float t = x[base+c] + y[base+c];
        v[i]=t; sum+=t; sq+=t*t;
    }
    #pragma unroll
    for(int off=32; off; off>>=1){ sum+=__shfl_xor(sum,off); sq+=__shfl_xor(sq,off); }
    __shared__ float s1[4], s2[4];
    int w = tid>>6;
    if((tid&63)==0){ s1[w]=sum; s2[w]=sq; }
    __syncthreads();
    sum = s1[0]+s1[1]+s1[2]+s1[3];
    sq  = s2[0]+s2[1]+s2[2]+s2[3];
    float m = sum*(1.f/768.f);
    float var = sq*(1.f/768.f) - m*m;
    float r = rsqrtf(var+LN_EPS);
    #pragma unroll
    for(int i=0;i<3;i++){
        int c = tid+i*256;
        x[base+c] = (v[i]-m)*r*g[c] + bta[c];
    }
}

// ---------------- in-place LN over 128 per row ----------------
__global__ void k_ln128(float* __restrict__ z, const float* __restrict__ g,
                        const float* __restrict__ bta){
    int row = blockIdx.x; int lane = threadIdx.x;
    size_t base = (size_t)row*EMB;
    float v0 = z[base+lane], v1 = z[base+lane+64];
    float sum = v0+v1, sq = v0*v0+v1*v1;
    #pragma unroll
    for(int off=32; off; off>>=1){ sum += __shfl_xor(sum,off); sq += __shfl_xor(sq,off); }
    float m = sum*(1.0f/128.0f);
    float var = sq*(1.0f/128.0f) - m*m;
    float r = rsqrtf(var + LN_EPS);
    z[base+lane]    = (v0-m)*r*g[lane]    + bta[lane];
    z[base+lane+64] = (v1-m)*r*g[lane+64] + bta[lane+64];
}

// ---------------- loss ----------------
// one wave per (t, b): pos = <z[s,b], zhat[s,b]>, neg = <LN(emb[neg_id]), zhat[s,b]>
__global__ void k_loss(const float* __restrict__ zout, const float* __restrict__ z,
                       const int* __restrict__ neg_ids, const float* __restrict__ emb,
                       const float* __restrict__ g, const float* __restrict__ bta,
                       float* __restrict__ loss)
{
    int bid = blockIdx.x;        // t*B + b
    int t = bid >> 2, b = bid & 3;
    int s = t + CW + 1;
    int lane = threadIdx.x;
    size_t hb = (size_t)(s*B_DIM+b)*EMB;
    float h0 = zout[hb+lane], h1 = zout[hb+lane+64];
    float p = z[hb+lane]*h0 + z[hb+lane+64]*h1;
    int nid = neg_ids[bid];
    const float* e = emb + (size_t)nid*EMB;
    float e0 = e[lane], e1 = e[lane+64];
    float sum = e0+e1, sq = e0*e0+e1*e1;
    #pragma unroll
    for(int off=32; off; off>>=1){
        p   += __shfl_xor(p,off);
        sum += __shfl_xor(sum,off);
        sq  += __shfl_xor(sq,off);
    }
    float m = sum*(1.f/128.f), var = sq*(1.f/128.f)-m*m, r = rsqrtf(var+LN_EPS);
    float zn0 = (e0-m)*r*g[lane]+bta[lane];
    float zn1 = (e1-m)*r*g[lane+64]+bta[lane+64];
    float n = zn0*h0 + zn1*h1;
    #pragma unroll
    for(int off=32; off; off>>=1) n += __shfl_xor(n,off);
    if(lane==0){
        float v = softplus_f(-p) + softplus_f(n);
        atomicAdd(loss, v * (1.0f/(2.0f*T_LEN*B_DIM)));
    }
}

extern "C" void kernel_launch(void* const* d_in, const int* in_sizes, int n_in,
                              void* d_out, int out_size, void* d_ws, size_t ws_size,
                              hipStream_t stream) {
    const int*   seq      = (const int*)  d_in[0];
    const int*   neg_ids  = (const int*)  d_in[1];
    const float* emb      = (const float*)d_in[2];
    const float* emb_ln_g = (const float*)d_in[3];
    const float* emb_ln_b = (const float*)d_in[4];
    const float* proj_w   = (const float*)d_in[5];
    const float* proj_b   = (const float*)d_in[6];
    const float* wqkv     = (const float*)d_in[7];
    const float* bqkv     = (const float*)d_in[8];
    const float* wo       = (const float*)d_in[9];
    const float* bo       = (const float*)d_in[10];
    const float* ln1_g    = (const float*)d_in[11];
    const float* ln1_b    = (const float*)d_in[12];
    const float* w1       = (const float*)d_in[13];
    const float* b1       = (const float*)d_in[14];
    const float* w2       = (const float*)d_in[15];
    const float* b2       = (const float*)d_in[16];
    const float* ln2_g    = (const float*)d_in[17];
    const float* ln2_b    = (const float*)d_in[18];
    const float* out_w    = (const float*)d_in[19];
    const float* out_b    = (const float*)d_in[20];
    const float* out_ln_g = (const float*)d_in[21];
    const float* out_ln_b = (const float*)d_in[22];

    // workspace carve-up (floats)
    size_t need = (size_t)(S_LEN*HID) + MROWS*EMB + (size_t)MROWS*HID
                + (size_t)MROWS*3072 + (size_t)MROWS*HID + MROWS*EMB;
    if (ws_size < need * sizeof(float)) return;  // loud failure: output stays 0

    float* ws   = (float*)d_ws;
    float* pe   = ws;  ws += S_LEN*HID;          // (S, HID)
    float* z    = ws;  ws += MROWS*EMB;          // (S*B, 128) embedded+LN
    float* x    = ws;  ws += (size_t)MROWS*HID;  // residual stream
    float* tmp  = ws;  ws += (size_t)MROWS*3072; // qkv (2304) / wo-out (768) / ff1 (3072)
    float* attno= ws;  ws += (size_t)MROWS*HID;  // attn out / ff2-out
    float* zout = ws;  ws += MROWS*EMB;          // (S*B, 128)

    hipMemsetAsync(d_out, 0, sizeof(float), stream);

    k_pe<<<(S_LEN*HID+255)/256, 256, 0, stream>>>(pe);
    k_embed_ln<<<MROWS, 64, 0, stream>>>(seq, emb, emb_ln_g, emb_ln_b, z);
    // tokens = gelu(z @ proj_w^T + proj_b) + pe  -> x
    k_gemm<2><<<dim3(HID/64, MROWS/64), 256, 0, stream>>>(z, proj_w, proj_b, x,
                                                          MROWS, HID, EMB, pe);
    for(int l=0; l<LAYERS; ++l){
        k_gemm<0><<<dim3(2304/64, MROWS/64), 256, 0, stream>>>(
            x, wqkv + (size_t)l*2304*HID, bqkv + l*2304, tmp, MROWS, 2304, HID, nullptr);
        k_attn<<<S_LEN*B_DIM*NHEAD, 64, 0, stream>>>(tmp, attno);
        k_gemm<0><<<dim3(HID/64, MROWS/64), 256, 0, stream>>>(
            attno, wo + (size_t)l*HID*HID, bo + l*HID, tmp, MROWS, HID, HID, nullptr);
        k_add_ln768<<<MROWS, 256, 0, stream>>>(x, tmp, ln1_g + l*HID, ln1_b + l*HID);
        k_gemm<1><<<dim3(3072/64, MROWS/64), 256, 0, stream>>>(
            x, w1 + (size_t)l*3072*HID, b1 + l*3072, tmp, MROWS, 3072, HID, nullptr);
        k_gemm<0><<<dim3(HID/64, MROWS/64), 256, 0, stream>>>(
            tmp, w2 + (size_t)l*HID*3072, b2 + l*HID, attno, MROWS, HID, 3072, nullptr);
        k_add_ln768<<<MROWS, 256, 0, stream>>>(x, attno, ln2_g + l*HID, ln2_b + l*HID);
    }
    k_gemm<0><<<dim3(EMB/64, MROWS/64), 256, 0, stream>>>(
        x, out_w, out_b, zout, MROWS, EMB, HID, nullptr);
    k_ln128<<<MROWS, 64, 0, stream>>>(zout, out_ln_g, out_ln_b);
    k_loss<<<T_LEN*B_DIM, 64, 0, stream>>>(zout, z, neg_ids, emb,
                                           emb_ln_g, emb_ln_b, (float*)d_out);
}

// Round 2
// 1286.015 us; speedup vs baseline: 3.8389x; 3.8389x over previous
//
#include <hip/hip_runtime.h>
#include <hip/hip_bf16.h>
#include <math.h>

#define S_LEN 1024
#define B_DIM 4
#define EMB 128
#define HID 768
#define LAYERS 4
#define CW 3
#define NHEAD 12
#define HDIM 64
#define T_LEN (S_LEN - 4*CW)   // 1012
#define LN_EPS 1e-5f
#define MROWS (S_LEN*B_DIM)    // 4096

typedef unsigned short u16;
typedef __attribute__((ext_vector_type(8))) __bf16 bf16x8;
typedef __attribute__((ext_vector_type(4))) float f32x4;

__device__ __forceinline__ u16 f2b(float f){
    unsigned u = __float_as_uint(f);
    u += 0x7fff + ((u >> 16) & 1);          // round-to-nearest-even
    return (u16)(u >> 16);
}
__device__ __forceinline__ float b2f(u16 h){
    return __uint_as_float(((unsigned)h) << 16);
}
__device__ __forceinline__ float gelu_exact(float x){
    return 0.5f * x * (1.0f + erff(x * 0.70710678118654752f));
}
__device__ __forceinline__ float softplus_f(float x){
    return fmaxf(x, 0.0f) + log1pf(expf(-fabsf(x)));
}

// ---------------- positional encoding table (S, HID) ----------------
__global__ void k_pe(float* __restrict__ pe){
    int idx = blockIdx.x*256 + threadIdx.x;
    if(idx >= S_LEN*HID) return;
    int s = idx / HID, c = idx % HID;
    int i2 = (c >> 1) * 2;
    float freq = expf(-(float)i2 * (logf(10000.0f) / (float)HID));
    float ang = (float)s * freq;
    pe[idx] = (c & 1) ? cosf(ang) : sinf(ang);
}

// ---------------- z = LN(emb_table[seq^T]) : f32 + bf16 copies ----------------
__global__ void k_embed_ln(const int* __restrict__ seq,
                           const float* __restrict__ emb,
                           const float* __restrict__ g,
                           const float* __restrict__ bta,
                           float* __restrict__ z, u16* __restrict__ zb){
    int row = blockIdx.x;
    int s = row >> 2, b = row & 3;
    int tok = seq[b*S_LEN + s];
    const float* e = emb + (size_t)tok * EMB;
    int lane = threadIdx.x;
    float v0 = e[lane], v1 = e[lane+64];
    float sum = v0+v1, sq = v0*v0+v1*v1;
    #pragma unroll
    for(int off=32; off; off>>=1){ sum += __shfl_xor(sum,off); sq += __shfl_xor(sq,off); }
    float m = sum * (1.0f/128.0f);
    float var = sq*(1.0f/128.0f) - m*m;
    float r = rsqrtf(var + LN_EPS);
    size_t base = (size_t)row*EMB;
    float o0 = (v0-m)*r*g[lane]    + bta[lane];
    float o1 = (v1-m)*r*g[lane+64] + bta[lane+64];
    z[base+lane] = o0; z[base+lane+64] = o1;
    zb[base+lane] = f2b(o0); zb[base+lane+64] = f2b(o1);
}

// ---------------- MFMA GEMM: C[M,N] = A_bf16[M,K] * Bw_f32[N,K]^T + bias ----------------
// 128x128 tile, BK=32, 256 threads (4 waves, each 64x64).
// A staged via global_load_lds (bf16 source); B reg-staged f32->bf16.
// EPI: 0 = +bias, 1 = gelu(+bias), 2 = gelu(+bias)+pe. WF/WB: write f32 / bf16 out.
template<int EPI, int WF, int WB>
__global__ __launch_bounds__(256) void k_mm(
    const u16*  __restrict__ A,
    const float* __restrict__ Bw,
    const float* __restrict__ bias,
    float* __restrict__ Cf, u16* __restrict__ Cb,
    int M, int N, int K, const float* __restrict__ pe)
{
    __shared__ u16 Al[128*32];
    __shared__ u16 Bl[128*32];
    int tid = threadIdx.x;
    int wave = tid >> 6, lane = tid & 63;
    int row0 = blockIdx.y * 128, col0 = blockIdx.x * 128;
    int wr = wave >> 1, wc = wave & 1;
    int lr = lane & 15, lk = lane >> 4;

    f32x4 acc[4][4];
    #pragma unroll
    for(int m=0;m<4;m++)
        #pragma unroll
        for(int n=0;n<4;n++) acc[m][n] = (f32x4){0.f,0.f,0.f,0.f};

    const char* Abase = (const char*)A;
    for(int k0 = 0; k0 < K; k0 += 32){
        // A: 128x32 bf16 (8 KB) via global_load_lds, 2 issues/thread
        #pragma unroll
        for(int i=0;i<2;i++){
            int p = i*4096 + wave*1024 + lane*16;   // byte offset in tile
            int r = p >> 6, cb = p & 63;
            const void* g = Abase + ((size_t)(row0+r)*K + k0)*2 + cb;
            void* l = (char*)Al + i*4096 + wave*1024;
            __builtin_amdgcn_global_load_lds(
                (const __attribute__((address_space(1))) void*)g,
                (__attribute__((address_space(3))) void*)l, 16, 0, 0);
        }
        // B: 128x32 f32 -> bf16, reg-staged
        #pragma unroll
        for(int j=0;j<4;j++){
            int q = j*256 + tid;                    // float4 index in tile
            int r = q >> 3, kc = (q & 7) * 4;
            float4 v = *(const float4*)(Bw + (size_t)(col0+r)*K + k0 + kc);
            ushort4 o;
            o.x = f2b(v.x); o.y = f2b(v.y); o.z = f2b(v.z); o.w = f2b(v.w);
            *(ushort4*)&Bl[r*32 + kc] = o;
        }
        __syncthreads();
        bf16x8 af[4], bfr[4];
        #pragma unroll
        for(int m=0;m<4;m++) af[m]  = *(const bf16x8*)&Al[(wr*64 + m*16 + lr)*32 + lk*8];
        #pragma unroll
        for(int n=0;n<4;n++) bfr[n] = *(const bf16x8*)&Bl[(wc*64 + n*16 + lr)*32 + lk*8];
        #pragma unroll
        for(int m=0;m<4;m++)
            #pragma unroll
            for(int n=0;n<4;n++)
                acc[m][n] = __builtin_amdgcn_mfma_f32_16x16x32_bf16(af[m], bfr[n], acc[m][n], 0, 0, 0);
        __syncthreads();
    }
    // epilogue: C/D layout col=lane&15, row=(lane>>4)*4+j
    #pragma unroll
    for(int m=0;m<4;m++){
        #pragma unroll
        for(int n=0;n<4;n++){
            #pragma unroll
            for(int j=0;j<4;j++){
                int row = row0 + wr*64 + m*16 + lk*4 + j;
                int col = col0 + wc*64 + n*16 + lr;
                float v = acc[m][n][j] + bias[col];
                if(EPI==1) v = gelu_exact(v);
                if(EPI==2) v = gelu_exact(v) + pe[(size_t)(row>>2)*HID + col];
                if(WF) Cf[(size_t)row*N + col] = v;
                if(WB) Cb[(size_t)row*N + col] = f2b(v);
            }
        }
    }
}

// ---------------- banded attention (bf16 qkv in, bf16 out) ----------------
__global__ void k_attn(const u16* __restrict__ qkv, u16* __restrict__ out){
    int bid = blockIdx.x;                 // s*(B*NHEAD) + b*NHEAD + h
    int h = bid % NHEAD;
    int b = (bid / NHEAD) & 3;
    int s = bid / (NHEAD*B_DIM);
    int lane = threadIdx.x;
    const float scale = 0.125f;
    float qd = b2f(qkv[((size_t)(s*B_DIM+b)*3*HID) + h*HDIM + lane]) * scale;
    float sc[13];
    #pragma unroll
    for(int g=0; g<13; ++g){
        sc[g] = -INFINITY;
        int t = s + g;
        if(g==6 || t >= S_LEN) continue;
        float kd = b2f(qkv[((size_t)(t*B_DIM+b)*3*HID) + HID + h*HDIM + lane]);
        float p = qd*kd;
        #pragma unroll
        for(int off=32; off; off>>=1) p += __shfl_xor(p, off);
        sc[g] = p;
    }
    float m = sc[0];
    #pragma unroll
    for(int g=1; g<13; ++g) m = fmaxf(m, sc[g]);
    float w[13]; float wsum = 0.f;
    #pragma unroll
    for(int g=0; g<13; ++g){ w[g] = expf(sc[g]-m); wsum += w[g]; }
    float accv = 0.f;
    #pragma unroll
    for(int g=0; g<13; ++g){
        int t = s + g;
        if(g==6 || t >= S_LEN) continue;
        accv += w[g] * b2f(qkv[((size_t)(t*B_DIM+b)*3*HID) + 2*HID + h*HDIM + lane]);
    }
    out[(size_t)(s*B_DIM+b)*HID + h*HDIM + lane] = f2b(accv / wsum);
}

// ---------------- x = LN(x + y) over 768; writes f32 x and bf16 xb ----------------
__global__ __launch_bounds__(256) void k_add_ln768(
    float* __restrict__ x, u16* __restrict__ xb, const float* __restrict__ y,
    const float* __restrict__ g, const float* __restrict__ bta)
{
    int row = blockIdx.x;
    size_t base = (size_t)row * HID;
    int tid = threadIdx.x;
    float v[3]; float sum=0.f, sq=0.f;
    #pragma unroll
    for(int i=0;i<3;i++){
        int c = tid + i*256;
        float t = x[base+c] + y[base+c];
        v[i]=t; sum+=t; sq+=t*t;
    }
    #pragma unroll
    for(int off=32; off; off>>=1){ sum+=__shfl_xor(sum,off); sq+=__shfl_xor(sq,off); }
    __shared__ float s1[4], s2[4];
    int w = tid>>6;
    if((tid&63)==0){ s1[w]=sum; s2[w]=sq; }
    __syncthreads();
    sum = s1[0]+s1[1]+s1[2]+s1[3];
    sq  = s2[0]+s2[1]+s2[2]+s2[3];
    float m = sum*(1.f/768.f);
    float var = sq*(1.f/768.f) - m*m;
    float r = rsqrtf(var+LN_EPS);
    #pragma unroll
    for(int i=0;i<3;i++){
        int c = tid+i*256;
        float o = (v[i]-m)*r*g[c] + bta[c];
        x[base+c] = o;
        xb[base+c] = f2b(o);
    }
}

// ---------------- in-place LN over 128 per row ----------------
__global__ void k_ln128(float* __restrict__ z, const float* __restrict__ g,
                        const float* __restrict__ bta){
    int row = blockIdx.x; int lane = threadIdx.x;
    size_t base = (size_t)row*EMB;
    float v0 = z[base+lane], v1 = z[base+lane+64];
    float sum = v0+v1, sq = v0*v0+v1*v1;
    #pragma unroll
    for(int off=32; off; off>>=1){ sum += __shfl_xor(sum,off); sq += __shfl_xor(sq,off); }
    float m = sum*(1.0f/128.0f);
    float var = sq*(1.0f/128.0f) - m*m;
    float r = rsqrtf(var + LN_EPS);
    z[base+lane]    = (v0-m)*r*g[lane]    + bta[lane];
    z[base+lane+64] = (v1-m)*r*g[lane+64] + bta[lane+64];
}

// ---------------- loss ----------------
__global__ void k_loss(const float* __restrict__ zout, const float* __restrict__ z,
                       const int* __restrict__ neg_ids, const float* __restrict__ emb,
                       const float* __restrict__ g, const float* __restrict__ bta,
                       float* __restrict__ loss)
{
    int bid = blockIdx.x;        // t*B + b
    int t = bid >> 2, b = bid & 3;
    int s = t + CW + 1;
    int lane = threadIdx.x;
    size_t hb = (size_t)(s*B_DIM+b)*EMB;
    float h0 = zout[hb+lane], h1 = zout[hb+lane+64];
    float p = z[hb+lane]*h0 + z[hb+lane+64]*h1;
    int nid = neg_ids[bid];
    const float* e = emb + (size_t)nid*EMB;
    float e0 = e[lane], e1 = e[lane+64];
    float sum = e0+e1, sq = e0*e0+e1*e1;
    #pragma unroll
    for(int off=32; off; off>>=1){
        p   += __shfl_xor(p,off);
        sum += __shfl_xor(sum,off);
        sq  += __shfl_xor(sq,off);
    }
    float m = sum*(1.f/128.f), var = sq*(1.f/128.f)-m*m, r = rsqrtf(var+LN_EPS);
    float zn0 = (e0-m)*r*g[lane]+bta[lane];
    float zn1 = (e1-m)*r*g[lane+64]+bta[lane+64];
    float n = zn0*h0 + zn1*h1;
    #pragma unroll
    for(int off=32; off; off>>=1) n += __shfl_xor(n,off);
    if(lane==0){
        float v = softplus_f(-p) + softplus_f(n);
        atomicAdd(loss, v * (1.0f/(2.0f*T_LEN*B_DIM)));
    }
}

extern "C" void kernel_launch(void* const* d_in, const int* in_sizes, int n_in,
                              void* d_out, int out_size, void* d_ws, size_t ws_size,
                              hipStream_t stream) {
    const int*   seq      = (const int*)  d_in[0];
    const int*   neg_ids  = (const int*)  d_in[1];
    const float* emb      = (const float*)d_in[2];
    const float* emb_ln_g = (const float*)d_in[3];
    const float* emb_ln_b = (const float*)d_in[4];
    const float* proj_w   = (const float*)d_in[5];
    const float* proj_b   = (const float*)d_in[6];
    const float* wqkv     = (const float*)d_in[7];
    const float* bqkv     = (const float*)d_in[8];
    const float* wo       = (const float*)d_in[9];
    const float* bo       = (const float*)d_in[10];
    const float* ln1_g    = (const float*)d_in[11];
    const float* ln1_b    = (const float*)d_in[12];
    const float* w1       = (const float*)d_in[13];
    const float* b1       = (const float*)d_in[14];
    const float* w2       = (const float*)d_in[15];
    const float* b2       = (const float*)d_in[16];
    const float* ln2_g    = (const float*)d_in[17];
    const float* ln2_b    = (const float*)d_in[18];
    const float* out_w    = (const float*)d_in[19];
    const float* out_b    = (const float*)d_in[20];
    const float* out_ln_g = (const float*)d_in[21];
    const float* out_ln_b = (const float*)d_in[22];

    // ---- workspace carve (bytes) ----
    char* p = (char*)d_ws;
    float* pe   = (float*)p; p += (size_t)S_LEN*HID*4;     // 3.1 MB
    float* z    = (float*)p; p += (size_t)MROWS*EMB*4;     // 2.1 MB
    float* x    = (float*)p; p += (size_t)MROWS*HID*4;     // 12.6 MB
    float* y    = (float*)p; p += (size_t)MROWS*HID*4;     // 12.6 MB
    float* zout = (float*)p; p += (size_t)MROWS*EMB*4;     // 2.1 MB
    u16*  z_b   = (u16*)p;   p += (size_t)MROWS*EMB*2;     // 1.0 MB
    u16*  x_b   = (u16*)p;   p += (size_t)MROWS*HID*2;     // 6.3 MB
    u16*  at_b  = (u16*)p;   p += (size_t)MROWS*HID*2;     // 6.3 MB
    u16*  big   = (u16*)p;   p += (size_t)MROWS*3072*2;    // 25.2 MB (qkv 2304 / ff 3072)
    size_t need = (size_t)(p - (char*)d_ws);
    if (ws_size < need) return;  // loud failure: output stays 0

    hipMemsetAsync(d_out, 0, sizeof(float), stream);

    k_pe<<<(S_LEN*HID+255)/256, 256, 0, stream>>>(pe);
    k_embed_ln<<<MROWS, 64, 0, stream>>>(seq, emb, emb_ln_g, emb_ln_b, z, z_b);
    // x = gelu(z @ proj_w^T + b) + pe   (f32 + bf16)
    k_mm<2,1,1><<<dim3(HID/128, MROWS/128), 256, 0, stream>>>(
        z_b, proj_w, proj_b, x, x_b, MROWS, HID, EMB, pe);
    for(int l=0; l<LAYERS; ++l){
        k_mm<0,0,1><<<dim3(2304/128, MROWS/128), 256, 0, stream>>>(
            x_b, wqkv + (size_t)l*2304*HID, bqkv + l*2304, nullptr, big,
            MROWS, 2304, HID, nullptr);
        k_attn<<<S_LEN*B_DIM*NHEAD, 64, 0, stream>>>(big, at_b);
        k_mm<0,1,0><<<dim3(HID/128, MROWS/128), 256, 0, stream>>>(
            at_b, wo + (size_t)l*HID*HID, bo + l*HID, y, nullptr,
            MROWS, HID, HID, nullptr);
        k_add_ln768<<<MROWS, 256, 0, stream>>>(x, x_b, y, ln1_g + l*HID, ln1_b + l*HID);
        k_mm<1,0,1><<<dim3(3072/128, MROWS/128), 256, 0, stream>>>(
            x_b, w1 + (size_t)l*3072*HID, b1 + l*3072, nullptr, big,
            MROWS, 3072, HID, nullptr);
        k_mm<0,1,0><<<dim3(HID/128, MROWS/128), 256, 0, stream>>>(
            big, w2 + (size_t)l*HID*3072, b2 + l*HID, y, nullptr,
            MROWS, HID, 3072, nullptr);
        k_add_ln768<<<MROWS, 256, 0, stream>>>(x, x_b, y, ln2_g + l*HID, ln2_b + l*HID);
    }
    k_mm<0,1,0><<<dim3(EMB/128, MROWS/128), 256, 0, stream>>>(
        x_b, out_w, out_b, zout, nullptr, MROWS, EMB, HID, nullptr);
    k_ln128<<<MROWS, 64, 0, stream>>>(zout, out_ln_g, out_ln_b);
    k_loss<<<T_LEN*B_DIM, 64, 0, stream>>>(zout, z, neg_ids, emb,
                                           emb_ln_g, emb_ln_b, (float*)d_out);
}

// Round 3
// 966.148 us; speedup vs baseline: 5.1098x; 1.3311x over previous
//
#include <hip/hip_runtime.h>
#include <hip/hip_bf16.h>
#include <math.h>

#define S_LEN 1024
#define B_DIM 4
#define EMB 128
#define HID 768
#define LAYERS 4
#define CW 3
#define NHEAD 12
#define HDIM 64
#define T_LEN (S_LEN - 4*CW)   // 1012
#define LN_EPS 1e-5f
#define MROWS (S_LEN*B_DIM)    // 4096

typedef unsigned short u16;
typedef __attribute__((ext_vector_type(8))) __bf16 bf16x8;
typedef __attribute__((ext_vector_type(4))) float f32x4;

__device__ __forceinline__ u16 f2b(float f){
    unsigned u = __float_as_uint(f);
    u += 0x7fff + ((u >> 16) & 1);          // round-to-nearest-even
    return (u16)(u >> 16);
}
__device__ __forceinline__ float b2f(u16 h){
    return __uint_as_float(((unsigned)h) << 16);
}
__device__ __forceinline__ float gelu_exact(float x){
    return 0.5f * x * (1.0f + erff(x * 0.70710678118654752f));
}
__device__ __forceinline__ float softplus_f(float x){
    return fmaxf(x, 0.0f) + log1pf(expf(-fabsf(x)));
}

// ---------------- f32 -> bf16 weight conversion ----------------
__global__ void k_cvt(const float* __restrict__ w, u16* __restrict__ o, int n4){
    int i = blockIdx.x*256 + threadIdx.x;
    if(i >= n4) return;
    float4 v = *(const float4*)(w + (size_t)i*4);
    ushort4 t; t.x=f2b(v.x); t.y=f2b(v.y); t.z=f2b(v.z); t.w=f2b(v.w);
    *(ushort4*)(o + (size_t)i*4) = t;
}

// ---------------- positional encoding table (S, HID) ----------------
__global__ void k_pe(float* __restrict__ pe){
    int idx = blockIdx.x*256 + threadIdx.x;
    if(idx >= S_LEN*HID) return;
    int s = idx / HID, c = idx % HID;
    int i2 = (c >> 1) * 2;
    float freq = expf(-(float)i2 * (logf(10000.0f) / (float)HID));
    float ang = (float)s * freq;
    pe[idx] = (c & 1) ? cosf(ang) : sinf(ang);
}

// ---------------- z = LN(emb_table[seq^T]) : f32 + bf16 copies ----------------
__global__ void k_embed_ln(const int* __restrict__ seq,
                           const float* __restrict__ emb,
                           const float* __restrict__ g,
                           const float* __restrict__ bta,
                           float* __restrict__ z, u16* __restrict__ zb){
    int row = blockIdx.x;
    int s = row >> 2, b = row & 3;
    int tok = seq[b*S_LEN + s];
    const float* e = emb + (size_t)tok * EMB;
    int lane = threadIdx.x;
    float v0 = e[lane], v1 = e[lane+64];
    float sum = v0+v1, sq = v0*v0+v1*v1;
    #pragma unroll
    for(int off=32; off; off>>=1){ sum += __shfl_xor(sum,off); sq += __shfl_xor(sq,off); }
    float m = sum * (1.0f/128.0f);
    float var = sq*(1.0f/128.0f) - m*m;
    float r = rsqrtf(var + LN_EPS);
    size_t base = (size_t)row*EMB;
    float o0 = (v0-m)*r*g[lane]    + bta[lane];
    float o1 = (v1-m)*r*g[lane+64] + bta[lane+64];
    z[base+lane] = o0; z[base+lane+64] = o1;
    zb[base+lane] = f2b(o0); zb[base+lane+64] = f2b(o1);
}

// ---------------- MFMA GEMM: C[M,N] = A_bf16[M,K] * B_bf16[N,K]^T + bias ----
// BMxBN tile, BK=32, 256 threads (4 waves, 2x2, per-wave BM/2 x BN/2).
// A and B staged via global_load_lds (16B) with pre-swizzled global source;
// reads XOR-swizzled: chunk ^= (row>>1)&3  -> 2-way (free) bank aliasing.
// EPI: 0 = +bias, 1 = gelu(+bias), 2 = gelu(+bias)+pe. WF/WB: write f32/bf16.
template<int BM, int BN, int EPI, int WF, int WB>
__global__ __launch_bounds__(256) void k_mm(
    const u16*  __restrict__ A,
    const u16*  __restrict__ Bw,
    const float* __restrict__ bias,
    float* __restrict__ Cf, u16* __restrict__ Cb,
    int M, int N, int K, const float* __restrict__ pe)
{
    constexpr int WM = BM/2, WN = BN/2, MR = WM/16, NR = WN/16;
    __shared__ u16 Al[BM*32];
    __shared__ u16 Bl[BN*32];
    int tid = threadIdx.x;
    int wave = tid >> 6, lane = tid & 63;

    // 1D grid: rows-slow / cols-fast ordering + bijective XCD chunk swizzle
    int nbx = N / BN, nby = M / BM, nwg = nbx * nby;
    int bid = blockIdx.x;
    int q = nwg >> 3, rm = nwg & 7, xcd = bid & 7, off = bid >> 3;
    int sbid = (xcd < rm ? xcd*(q+1) : rm*(q+1) + (xcd-rm)*q) + off;
    int row0 = (sbid / nbx) * BM, col0 = (sbid % nbx) * BN;

    int wr = wave >> 1, wc = wave & 1;
    int lr = lane & 15, lk = lane >> 4;

    f32x4 acc[MR][NR];
    #pragma unroll
    for(int m=0;m<MR;m++)
        #pragma unroll
        for(int n=0;n<NR;n++) acc[m][n] = (f32x4){0.f,0.f,0.f,0.f};

    const char* Abase = (const char*)A;
    const char* Bbase = (const char*)Bw;
    for(int k0 = 0; k0 < K; k0 += 32){
        // A: BM x 32 bf16 tile via global_load_lds, source chunk pre-swizzled
        #pragma unroll
        for(int i=0;i<BM/64;i++){
            int p = i*4096 + wave*1024 + lane*16;       // byte offset in tile
            int rr = p >> 6, u = (p >> 4) & 3;
            int us = u ^ ((rr >> 1) & 3);
            const char* g = Abase + ((size_t)(row0+rr)*K + k0)*2 + us*16;
            void* l = (char*)Al + i*4096 + wave*1024;   // wave-uniform base
            __builtin_amdgcn_global_load_lds(
                (const __attribute__((address_space(1))) void*)g,
                (__attribute__((address_space(3))) void*)l, 16, 0, 0);
        }
        // B: BN x 32 bf16 tile, same path
        #pragma unroll
        for(int i=0;i<BN/64;i++){
            int p = i*4096 + wave*1024 + lane*16;
            int rr = p >> 6, u = (p >> 4) & 3;
            int us = u ^ ((rr >> 1) & 3);
            const char* g = Bbase + ((size_t)(col0+rr)*K + k0)*2 + us*16;
            void* l = (char*)Bl + i*4096 + wave*1024;
            __builtin_amdgcn_global_load_lds(
                (const __attribute__((address_space(1))) void*)g,
                (__attribute__((address_space(3))) void*)l, 16, 0, 0);
        }
        __syncthreads();
        bf16x8 af[MR], bfr[NR];
        #pragma unroll
        for(int m=0;m<MR;m++){
            int ar = wr*WM + m*16 + lr;
            af[m] = *(const bf16x8*)((const char*)Al + ar*64 + ((lk ^ ((ar>>1)&3))<<4));
        }
        #pragma unroll
        for(int n=0;n<NR;n++){
            int br = wc*WN + n*16 + lr;
            bfr[n] = *(const bf16x8*)((const char*)Bl + br*64 + ((lk ^ ((br>>1)&3))<<4));
        }
        #pragma unroll
        for(int m=0;m<MR;m++)
            #pragma unroll
            for(int n=0;n<NR;n++)
                acc[m][n] = __builtin_amdgcn_mfma_f32_16x16x32_bf16(af[m], bfr[n], acc[m][n], 0, 0, 0);
        __syncthreads();
    }
    // epilogue: C/D layout col=lane&15, row=(lane>>4)*4+j
    #pragma unroll
    for(int m=0;m<MR;m++){
        #pragma unroll
        for(int n=0;n<NR;n++){
            #pragma unroll
            for(int j=0;j<4;j++){
                int row = row0 + wr*WM + m*16 + lk*4 + j;
                int col = col0 + wc*WN + n*16 + lr;
                float v = acc[m][n][j] + bias[col];
                if(EPI==1) v = gelu_exact(v);
                if(EPI==2) v = gelu_exact(v) + pe[(size_t)(row>>2)*HID + col];
                if(WF) Cf[(size_t)row*N + col] = v;
                if(WB) Cb[(size_t)row*N + col] = f2b(v);
            }
        }
    }
}

// ---------------- banded attention (bf16 qkv in, bf16 out) ----------------
__global__ void k_attn(const u16* __restrict__ qkv, u16* __restrict__ out){
    int bid = blockIdx.x;                 // s*(B*NHEAD) + b*NHEAD + h
    int h = bid % NHEAD;
    int b = (bid / NHEAD) & 3;
    int s = bid / (NHEAD*B_DIM);
    int lane = threadIdx.x;
    const float scale = 0.125f;
    float qd = b2f(qkv[((size_t)(s*B_DIM+b)*3*HID) + h*HDIM + lane]) * scale;
    float sc[13];
    #pragma unroll
    for(int g=0; g<13; ++g){
        sc[g] = -INFINITY;
        int t = s + g;
        if(g==6 || t >= S_LEN) continue;
        float kd = b2f(qkv[((size_t)(t*B_DIM+b)*3*HID) + HID + h*HDIM + lane]);
        float p = qd*kd;
        #pragma unroll
        for(int off=32; off; off>>=1) p += __shfl_xor(p, off);
        sc[g] = p;
    }
    float m = sc[0];
    #pragma unroll
    for(int g=1; g<13; ++g) m = fmaxf(m, sc[g]);
    float w[13]; float wsum = 0.f;
    #pragma unroll
    for(int g=0; g<13; ++g){ w[g] = expf(sc[g]-m); wsum += w[g]; }
    float accv = 0.f;
    #pragma unroll
    for(int g=0; g<13; ++g){
        int t = s + g;
        if(g==6 || t >= S_LEN) continue;
        accv += w[g] * b2f(qkv[((size_t)(t*B_DIM+b)*3*HID) + 2*HID + h*HDIM + lane]);
    }
    out[(size_t)(s*B_DIM+b)*HID + h*HDIM + lane] = f2b(accv / wsum);
}

// ---------------- x = LN(x + y_b16) over 768; writes f32 x and bf16 xb ------
__global__ __launch_bounds__(256) void k_add_ln768(
    float* __restrict__ x, u16* __restrict__ xb, const u16* __restrict__ y,
    const float* __restrict__ g, const float* __restrict__ bta)
{
    int row = blockIdx.x;
    size_t base = (size_t)row * HID;
    int tid = threadIdx.x;
    float v[3]; float sum=0.f, sq=0.f;
    #pragma unroll
    for(int i=0;i<3;i++){
        int c = tid + i*256;
        float t = x[base+c] + b2f(y[base+c]);
        v[i]=t; sum+=t; sq+=t*t;
    }
    #pragma unroll
    for(int off=32; off; off>>=1){ sum+=__shfl_xor(sum,off); sq+=__shfl_xor(sq,off); }
    __shared__ float s1[4], s2[4];
    int w = tid>>6;
    if((tid&63)==0){ s1[w]=sum; s2[w]=sq; }
    __syncthreads();
    sum = s1[0]+s1[1]+s1[2]+s1[3];
    sq  = s2[0]+s2[1]+s2[2]+s2[3];
    float m = sum*(1.f/768.f);
    float var = sq*(1.f/768.f) - m*m;
    float r = rsqrtf(var+LN_EPS);
    #pragma unroll
    for(int i=0;i<3;i++){
        int c = tid+i*256;
        float o = (v[i]-m)*r*g[c] + bta[c];
        x[base+c] = o;
        xb[base+c] = f2b(o);
    }
}

// ---------------- in-place LN over 128 per row ----------------
__global__ void k_ln128(float* __restrict__ z, const float* __restrict__ g,
                        const float* __restrict__ bta){
    int row = blockIdx.x; int lane = threadIdx.x;
    size_t base = (size_t)row*EMB;
    float v0 = z[base+lane], v1 = z[base+lane+64];
    float sum = v0+v1, sq = v0*v0+v1*v1;
    #pragma unroll
    for(int off=32; off; off>>=1){ sum += __shfl_xor(sum,off); sq += __shfl_xor(sq,off); }
    float m = sum*(1.0f/128.0f);
    float var = sq*(1.0f/128.0f) - m*m;
    float r = rsqrtf(var + LN_EPS);
    z[base+lane]    = (v0-m)*r*g[lane]    + bta[lane];
    z[base+lane+64] = (v1-m)*r*g[lane+64] + bta[lane+64];
}

// ---------------- loss ----------------
__global__ void k_loss(const float* __restrict__ zout, const float* __restrict__ z,
                       const int* __restrict__ neg_ids, const float* __restrict__ emb,
                       const float* __restrict__ g, const float* __restrict__ bta,
                       float* __restrict__ loss)
{
    int bid = blockIdx.x;        // t*B + b
    int t = bid >> 2, b = bid & 3;
    int s = t + CW + 1;
    int lane = threadIdx.x;
    size_t hb = (size_t)(s*B_DIM+b)*EMB;
    float h0 = zout[hb+lane], h1 = zout[hb+lane+64];
    float p = z[hb+lane]*h0 + z[hb+lane+64]*h1;
    int nid = neg_ids[bid];
    const float* e = emb + (size_t)nid*EMB;
    float e0 = e[lane], e1 = e[lane+64];
    float sum = e0+e1, sq = e0*e0+e1*e1;
    #pragma unroll
    for(int off=32; off; off>>=1){
        p   += __shfl_xor(p,off);
        sum += __shfl_xor(sum,off);
        sq  += __shfl_xor(sq,off);
    }
    float m = sum*(1.f/128.f), var = sq*(1.f/128.f)-m*m, r = rsqrtf(var+LN_EPS);
    float zn0 = (e0-m)*r*g[lane]+bta[lane];
    float zn1 = (e1-m)*r*g[lane+64]+bta[lane+64];
    float n = zn0*h0 + zn1*h1;
    #pragma unroll
    for(int off=32; off; off>>=1) n += __shfl_xor(n,off);
    if(lane==0){
        float v = softplus_f(-p) + softplus_f(n);
        atomicAdd(loss, v * (1.0f/(2.0f*T_LEN*B_DIM)));
    }
}

static inline int cvt_grid(int n){ return (n/4 + 255)/256; }

extern "C" void kernel_launch(void* const* d_in, const int* in_sizes, int n_in,
                              void* d_out, int out_size, void* d_ws, size_t ws_size,
                              hipStream_t stream) {
    const int*   seq      = (const int*)  d_in[0];
    const int*   neg_ids  = (const int*)  d_in[1];
    const float* emb      = (const float*)d_in[2];
    const float* emb_ln_g = (const float*)d_in[3];
    const float* emb_ln_b = (const float*)d_in[4];
    const float* proj_w   = (const float*)d_in[5];
    const float* proj_b   = (const float*)d_in[6];
    const float* wqkv     = (const float*)d_in[7];
    const float* bqkv     = (const float*)d_in[8];
    const float* wo       = (const float*)d_in[9];
    const float* bo       = (const float*)d_in[10];
    const float* ln1_g    = (const float*)d_in[11];
    const float* ln1_b    = (const float*)d_in[12];
    const float* w1       = (const float*)d_in[13];
    const float* b1       = (const float*)d_in[14];
    const float* w2       = (const float*)d_in[15];
    const float* b2       = (const float*)d_in[16];
    const float* ln2_g    = (const float*)d_in[17];
    const float* ln2_b    = (const float*)d_in[18];
    const float* out_w    = (const float*)d_in[19];
    const float* out_b    = (const float*)d_in[20];
    const float* out_ln_g = (const float*)d_in[21];
    const float* out_ln_b = (const float*)d_in[22];

    // ---- workspace carve (bytes) ----
    char* p = (char*)d_ws;
    float* pe   = (float*)p; p += (size_t)S_LEN*HID*4;     // 3.1 MB
    float* z    = (float*)p; p += (size_t)MROWS*EMB*4;     // 2.1 MB
    float* x    = (float*)p; p += (size_t)MROWS*HID*4;     // 12.6 MB
    float* zout = (float*)p; p += (size_t)MROWS*EMB*4;     // 2.1 MB
    u16*  z_b   = (u16*)p;   p += (size_t)MROWS*EMB*2;     // 1.0 MB
    u16*  x_b   = (u16*)p;   p += (size_t)MROWS*HID*2;     // 6.3 MB
    u16*  at_b  = (u16*)p;   p += (size_t)MROWS*HID*2;     // 6.3 MB
    u16*  y_b   = (u16*)p;   p += (size_t)MROWS*HID*2;     // 6.3 MB
    u16*  big   = (u16*)p;   p += (size_t)MROWS*3072*2;    // 25.2 MB
    u16*  wscr  = (u16*)p;   p += (size_t)3072*HID*2;      // 4.7 MB weight scratch
    size_t need = (size_t)(p - (char*)d_ws);
    if (ws_size < need) return;  // loud failure: output stays 0

    hipMemsetAsync(d_out, 0, sizeof(float), stream);

    k_pe<<<(S_LEN*HID+255)/256, 256, 0, stream>>>(pe);
    k_embed_ln<<<MROWS, 64, 0, stream>>>(seq, emb, emb_ln_g, emb_ln_b, z, z_b);

    // x = gelu(z @ proj_w^T + b) + pe   (f32 + bf16)
    k_cvt<<<cvt_grid(HID*EMB), 256, 0, stream>>>(proj_w, wscr, HID*EMB/4);
    k_mm<64,64,2,1,1><<<(768/64)*(MROWS/64), 256, 0, stream>>>(
        z_b, wscr, proj_b, x, x_b, MROWS, HID, EMB, pe);

    for(int l=0; l<LAYERS; ++l){
        k_cvt<<<cvt_grid(2304*HID), 256, 0, stream>>>(wqkv + (size_t)l*2304*HID, wscr, 2304*HID/4);
        k_mm<128,128,0,0,1><<<(2304/128)*(MROWS/128), 256, 0, stream>>>(
            x_b, wscr, bqkv + l*2304, nullptr, big, MROWS, 2304, HID, nullptr);
        k_attn<<<S_LEN*B_DIM*NHEAD, 64, 0, stream>>>(big, at_b);
        k_cvt<<<cvt_grid(HID*HID), 256, 0, stream>>>(wo + (size_t)l*HID*HID, wscr, HID*HID/4);
        k_mm<64,64,0,0,1><<<(768/64)*(MROWS/64), 256, 0, stream>>>(
            at_b, wscr, bo + l*HID, nullptr, y_b, MROWS, HID, HID, nullptr);
        k_add_ln768<<<MROWS, 256, 0, stream>>>(x, x_b, y_b, ln1_g + l*HID, ln1_b + l*HID);
        k_cvt<<<cvt_grid(3072*HID), 256, 0, stream>>>(w1 + (size_t)l*3072*HID, wscr, 3072*HID/4);
        k_mm<128,128,1,0,1><<<(3072/128)*(MROWS/128), 256, 0, stream>>>(
            x_b, wscr, b1 + l*3072, nullptr, big, MROWS, 3072, HID, nullptr);
        k_cvt<<<cvt_grid(3072*HID), 256, 0, stream>>>(w2 + (size_t)l*HID*3072, wscr, 3072*HID/4);
        k_mm<64,64,0,0,1><<<(768/64)*(MROWS/64), 256, 0, stream>>>(
            big, wscr, b2 + l*HID, nullptr, y_b, MROWS, HID, 3072, nullptr);
        k_add_ln768<<<MROWS, 256, 0, stream>>>(x, x_b, y_b, ln2_g + l*HID, ln2_b + l*HID);
    }
    k_cvt<<<cvt_grid(EMB*HID), 256, 0, stream>>>(out_w, wscr, EMB*HID/4);
    k_mm<64,64,0,1,0><<<(EMB/64)*(MROWS/64), 256, 0, stream>>>(
        x_b, wscr, out_b, zout, nullptr, MROWS, EMB, HID, nullptr);
    k_ln128<<<MROWS, 64, 0, stream>>>(zout, out_ln_g, out_ln_b);
    k_loss<<<T_LEN*B_DIM, 64, 0, stream>>>(zout, z, neg_ids, emb,
                                           emb_ln_g, emb_ln_b, (float*)d_out);
}

// Round 4
// 952.366 us; speedup vs baseline: 5.1838x; 1.0145x over previous
//
#include <hip/hip_runtime.h>
#include <hip/hip_bf16.h>
#include <math.h>

#define S_LEN 1024
#define B_DIM 4
#define EMB 128
#define HID 768
#define LAYERS 4
#define CW 3
#define NHEAD 12
#define HDIM 64
#define T_LEN (S_LEN - 4*CW)   // 1012
#define LN_EPS 1e-5f
#define MROWS (S_LEN*B_DIM)    // 4096

typedef unsigned short u16;
typedef __attribute__((ext_vector_type(8))) __bf16 bf16x8;
typedef __attribute__((ext_vector_type(4))) float f32x4;

__device__ __forceinline__ u16 f2b(float f){
    unsigned u = __float_as_uint(f);
    u += 0x7fff + ((u >> 16) & 1);          // round-to-nearest-even
    return (u16)(u >> 16);
}
__device__ __forceinline__ float b2f(u16 h){
    return __uint_as_float(((unsigned)h) << 16);
}
__device__ __forceinline__ float gelu_exact(float x){
    return 0.5f * x * (1.0f + erff(x * 0.70710678118654752f));
}
__device__ __forceinline__ float softplus_f(float x){
    return fmaxf(x, 0.0f) + log1pf(expf(-fabsf(x)));
}

// ---------------- f32 -> bf16 weight conversion ----------------
__global__ void k_cvt(const float* __restrict__ w, u16* __restrict__ o, int n4){
    int i = blockIdx.x*256 + threadIdx.x;
    if(i >= n4) return;
    float4 v = *(const float4*)(w + (size_t)i*4);
    ushort4 t; t.x=f2b(v.x); t.y=f2b(v.y); t.z=f2b(v.z); t.w=f2b(v.w);
    *(ushort4*)(o + (size_t)i*4) = t;
}

// ---------------- positional encoding table (S, HID) ----------------
__global__ void k_pe(float* __restrict__ pe){
    int idx = blockIdx.x*256 + threadIdx.x;
    if(idx >= S_LEN*HID) return;
    int s = idx / HID, c = idx % HID;
    int i2 = (c >> 1) * 2;
    float freq = expf(-(float)i2 * (logf(10000.0f) / (float)HID));
    float ang = (float)s * freq;
    pe[idx] = (c & 1) ? cosf(ang) : sinf(ang);
}

// ---------------- z = LN(emb_table[seq^T]) : f32 + bf16 copies ----------------
__global__ void k_embed_ln(const int* __restrict__ seq,
                           const float* __restrict__ emb,
                           const float* __restrict__ g,
                           const float* __restrict__ bta,
                           float* __restrict__ z, u16* __restrict__ zb){
    int row = blockIdx.x;
    int s = row >> 2, b = row & 3;
    int tok = seq[b*S_LEN + s];
    const float* e = emb + (size_t)tok * EMB;
    int lane = threadIdx.x;
    float v0 = e[lane], v1 = e[lane+64];
    float sum = v0+v1, sq = v0*v0+v1*v1;
    #pragma unroll
    for(int off=32; off; off>>=1){ sum += __shfl_xor(sum,off); sq += __shfl_xor(sq,off); }
    float m = sum * (1.0f/128.0f);
    float var = sq*(1.0f/128.0f) - m*m;
    float r = rsqrtf(var + LN_EPS);
    size_t base = (size_t)row*EMB;
    float o0 = (v0-m)*r*g[lane]    + bta[lane];
    float o1 = (v1-m)*r*g[lane+64] + bta[lane+64];
    z[base+lane] = o0; z[base+lane+64] = o1;
    zb[base+lane] = f2b(o0); zb[base+lane+64] = f2b(o1);
}

// ---------------- MFMA GEMM: C[M,N] = A_bf16[M,K] * B_bf16[N,K]^T + bias ----
// BMxBN tile, BK=32, 256 threads (4 waves, 2x2, per-wave BM/2 x BN/2).
// Double-buffered LDS; tile t+1 staged via global_load_lds BEFORE computing
// tile t; raw s_barrier + counted s_waitcnt vmcnt(IC) so next-tile loads stay
// in flight across the barrier (T3 minimum-2-phase recipe).
// Source chunk pre-swizzled (chunk ^= (row>>1)&3), same XOR on ds_read side.
// EPI: 0 = +bias, 1 = gelu(+bias), 2 = gelu(+bias)+pe. WF/WB: write f32/bf16.
template<int BM, int BN, int EPI, int WF, int WB>
__global__ __launch_bounds__(256) void k_mm(
    const u16*  __restrict__ A,
    const u16*  __restrict__ Bw,
    const float* __restrict__ bias,
    float* __restrict__ Cf, u16* __restrict__ Cb,
    int M, int N, int K, const float* __restrict__ pe)
{
    constexpr int WM = BM/2, WN = BN/2, MR = WM/16, NR = WN/16;
    constexpr int IC = BM/64 + BN/64;       // gload_lds issues per thread/tile
    __shared__ u16 Al[2][BM*32];
    __shared__ u16 Bl[2][BN*32];
    int tid = threadIdx.x;
    int wave = tid >> 6, lane = tid & 63;

    // 1D grid: rows-slow / cols-fast ordering + bijective XCD chunk swizzle
    int nbx = N / BN, nby = M / BM, nwg = nbx * nby;
    int bid = blockIdx.x;
    int q = nwg >> 3, rm = nwg & 7, xcd = bid & 7, off = bid >> 3;
    int sbid = (xcd < rm ? xcd*(q+1) : rm*(q+1) + (xcd-rm)*q) + off;
    int row0 = (sbid / nbx) * BM, col0 = (sbid % nbx) * BN;

    int wr = wave >> 1, wc = wave & 1;
    int lr = lane & 15, lk = lane >> 4;

    f32x4 acc[MR][NR];
    #pragma unroll
    for(int m=0;m<MR;m++)
        #pragma unroll
        for(int n=0;n<NR;n++) acc[m][n] = (f32x4){0.f,0.f,0.f,0.f};

    const char* Abase = (const char*)A;
    const char* Bbase = (const char*)Bw;

    auto stage = [&](int buf, int k0){
        #pragma unroll
        for(int i=0;i<BM/64;i++){
            int p = i*4096 + wave*1024 + lane*16;       // byte offset in tile
            int rr = p >> 6, u = (p >> 4) & 3;
            int us = u ^ ((rr >> 1) & 3);
            const char* g = Abase + ((size_t)(row0+rr)*K + k0)*2 + us*16;
            void* l = (char*)&Al[buf][0] + i*4096 + wave*1024;  // wave-uniform
            __builtin_amdgcn_global_load_lds(
                (const __attribute__((address_space(1))) void*)g,
                (__attribute__((address_space(3))) void*)l, 16, 0, 0);
        }
        #pragma unroll
        for(int i=0;i<BN/64;i++){
            int p = i*4096 + wave*1024 + lane*16;
            int rr = p >> 6, u = (p >> 4) & 3;
            int us = u ^ ((rr >> 1) & 3);
            const char* g = Bbase + ((size_t)(col0+rr)*K + k0)*2 + us*16;
            void* l = (char*)&Bl[buf][0] + i*4096 + wave*1024;
            __builtin_amdgcn_global_load_lds(
                (const __attribute__((address_space(1))) void*)g,
                (__attribute__((address_space(3))) void*)l, 16, 0, 0);
        }
    };

    int nt = K >> 5;
    stage(0, 0);
    for(int t=0; t<nt; ++t){
        int cur = t & 1;
        bool hasnext = (t+1 < nt);
        if(hasnext) stage(cur^1, (t+1) << 5);
        // wait for CURRENT tile's loads; leave next tile's IC loads in flight
        if(hasnext){
            if constexpr (IC==4) asm volatile("s_waitcnt vmcnt(4)" ::: "memory");
            else if constexpr (IC==3) asm volatile("s_waitcnt vmcnt(3)" ::: "memory");
            else asm volatile("s_waitcnt vmcnt(2)" ::: "memory");
        } else {
            asm volatile("s_waitcnt vmcnt(0)" ::: "memory");
        }
        __builtin_amdgcn_s_barrier();
        __builtin_amdgcn_sched_barrier(0);
        bf16x8 af[MR], bfr[NR];
        #pragma unroll
        for(int m=0;m<MR;m++){
            int ar = wr*WM + m*16 + lr;
            af[m] = *(const bf16x8*)((const char*)&Al[cur][0] + ar*64 + ((lk ^ ((ar>>1)&3))<<4));
        }
        #pragma unroll
        for(int n=0;n<NR;n++){
            int br = wc*WN + n*16 + lr;
            bfr[n] = *(const bf16x8*)((const char*)&Bl[cur][0] + br*64 + ((lk ^ ((br>>1)&3))<<4));
        }
        #pragma unroll
        for(int m=0;m<MR;m++)
            #pragma unroll
            for(int n=0;n<NR;n++)
                acc[m][n] = __builtin_amdgcn_mfma_f32_16x16x32_bf16(af[m], bfr[n], acc[m][n], 0, 0, 0);
        __builtin_amdgcn_s_barrier();   // all waves done reading buf cur
    }
    // epilogue: C/D layout col=lane&15, row=(lane>>4)*4+j
    #pragma unroll
    for(int m=0;m<MR;m++){
        #pragma unroll
        for(int n=0;n<NR;n++){
            #pragma unroll
            for(int j=0;j<4;j++){
                int row = row0 + wr*WM + m*16 + lk*4 + j;
                int col = col0 + wc*WN + n*16 + lr;
                float v = acc[m][n][j] + bias[col];
                if(EPI==1) v = gelu_exact(v);
                if(EPI==2) v = gelu_exact(v) + pe[(size_t)(row>>2)*HID + col];
                if(WF) Cf[(size_t)row*N + col] = v;
                if(WB) Cb[(size_t)row*N + col] = f2b(v);
            }
        }
    }
}

// ---------------- banded attention (bf16 qkv in, bf16 out) ----------------
__global__ void k_attn(const u16* __restrict__ qkv, u16* __restrict__ out){
    int bid = blockIdx.x;                 // s*(B*NHEAD) + b*NHEAD + h
    int h = bid % NHEAD;
    int b = (bid / NHEAD) & 3;
    int s = bid / (NHEAD*B_DIM);
    int lane = threadIdx.x;
    const float scale = 0.125f;
    float qd = b2f(qkv[((size_t)(s*B_DIM+b)*3*HID) + h*HDIM + lane]) * scale;
    float sc[13];
    #pragma unroll
    for(int g=0; g<13; ++g){
        sc[g] = -INFINITY;
        int t = s + g;
        if(g==6 || t >= S_LEN) continue;
        float kd = b2f(qkv[((size_t)(t*B_DIM+b)*3*HID) + HID + h*HDIM + lane]);
        float p = qd*kd;
        #pragma unroll
        for(int off=32; off; off>>=1) p += __shfl_xor(p, off);
        sc[g] = p;
    }
    float m = sc[0];
    #pragma unroll
    for(int g=1; g<13; ++g) m = fmaxf(m, sc[g]);
    float w[13]; float wsum = 0.f;
    #pragma unroll
    for(int g=0; g<13; ++g){ w[g] = expf(sc[g]-m); wsum += w[g]; }
    float accv = 0.f;
    #pragma unroll
    for(int g=0; g<13; ++g){
        int t = s + g;
        if(g==6 || t >= S_LEN) continue;
        accv += w[g] * b2f(qkv[((size_t)(t*B_DIM+b)*3*HID) + 2*HID + h*HDIM + lane]);
    }
    out[(size_t)(s*B_DIM+b)*HID + h*HDIM + lane] = f2b(accv / wsum);
}

// ---------------- x = LN(x + y_b16) over 768; writes f32 x and bf16 xb ------
__global__ __launch_bounds__(256) void k_add_ln768(
    float* __restrict__ x, u16* __restrict__ xb, const u16* __restrict__ y,
    const float* __restrict__ g, const float* __restrict__ bta)
{
    int row = blockIdx.x;
    size_t base = (size_t)row * HID;
    int tid = threadIdx.x;
    float v[3]; float sum=0.f, sq=0.f;
    #pragma unroll
    for(int i=0;i<3;i++){
        int c = tid + i*256;
        float t = x[base+c] + b2f(y[base+c]);
        v[i]=t; sum+=t; sq+=t*t;
    }
    #pragma unroll
    for(int off=32; off; off>>=1){ sum+=__shfl_xor(sum,off); sq+=__shfl_xor(sq,off); }
    __shared__ float s1[4], s2[4];
    int w = tid>>6;
    if((tid&63)==0){ s1[w]=sum; s2[w]=sq; }
    __syncthreads();
    sum = s1[0]+s1[1]+s1[2]+s1[3];
    sq  = s2[0]+s2[1]+s2[2]+s2[3];
    float m = sum*(1.f/768.f);
    float var = sq*(1.f/768.f) - m*m;
    float r = rsqrtf(var+LN_EPS);
    #pragma unroll
    for(int i=0;i<3;i++){
        int c = tid+i*256;
        float o = (v[i]-m)*r*g[c] + bta[c];
        x[base+c] = o;
        xb[base+c] = f2b(o);
    }
}

// ---------------- in-place LN over 128 per row ----------------
__global__ void k_ln128(float* __restrict__ z, const float* __restrict__ g,
                        const float* __restrict__ bta){
    int row = blockIdx.x; int lane = threadIdx.x;
    size_t base = (size_t)row*EMB;
    float v0 = z[base+lane], v1 = z[base+lane+64];
    float sum = v0+v1, sq = v0*v0+v1*v1;
    #pragma unroll
    for(int off=32; off; off>>=1){ sum += __shfl_xor(sum,off); sq += __shfl_xor(sq,off); }
    float m = sum*(1.0f/128.0f);
    float var = sq*(1.0f/128.0f) - m*m;
    float r = rsqrtf(var + LN_EPS);
    z[base+lane]    = (v0-m)*r*g[lane]    + bta[lane];
    z[base+lane+64] = (v1-m)*r*g[lane+64] + bta[lane+64];
}

// ---------------- loss ----------------
__global__ void k_loss(const float* __restrict__ zout, const float* __restrict__ z,
                       const int* __restrict__ neg_ids, const float* __restrict__ emb,
                       const float* __restrict__ g, const float* __restrict__ bta,
                       float* __restrict__ loss)
{
    int bid = blockIdx.x;        // t*B + b
    int t = bid >> 2, b = bid & 3;
    int s = t + CW + 1;
    int lane = threadIdx.x;
    size_t hb = (size_t)(s*B_DIM+b)*EMB;
    float h0 = zout[hb+lane], h1 = zout[hb+lane+64];
    float p = z[hb+lane]*h0 + z[hb+lane+64]*h1;
    int nid = neg_ids[bid];
    const float* e = emb + (size_t)nid*EMB;
    float e0 = e[lane], e1 = e[lane+64];
    float sum = e0+e1, sq = e0*e0+e1*e1;
    #pragma unroll
    for(int off=32; off; off>>=1){
        p   += __shfl_xor(p,off);
        sum += __shfl_xor(sum,off);
        sq  += __shfl_xor(sq,off);
    }
    float m = sum*(1.f/128.f), var = sq*(1.f/128.f)-m*m, r = rsqrtf(var+LN_EPS);
    float zn0 = (e0-m)*r*g[lane]+bta[lane];
    float zn1 = (e1-m)*r*g[lane+64]+bta[lane+64];
    float n = zn0*h0 + zn1*h1;
    #pragma unroll
    for(int off=32; off; off>>=1) n += __shfl_xor(n,off);
    if(lane==0){
        float v = softplus_f(-p) + softplus_f(n);
        atomicAdd(loss, v * (1.0f/(2.0f*T_LEN*B_DIM)));
    }
}

static inline int cvt_grid(int n){ return (n/4 + 255)/256; }

extern "C" void kernel_launch(void* const* d_in, const int* in_sizes, int n_in,
                              void* d_out, int out_size, void* d_ws, size_t ws_size,
                              hipStream_t stream) {
    const int*   seq      = (const int*)  d_in[0];
    const int*   neg_ids  = (const int*)  d_in[1];
    const float* emb      = (const float*)d_in[2];
    const float* emb_ln_g = (const float*)d_in[3];
    const float* emb_ln_b = (const float*)d_in[4];
    const float* proj_w   = (const float*)d_in[5];
    const float* proj_b   = (const float*)d_in[6];
    const float* wqkv     = (const float*)d_in[7];
    const float* bqkv     = (const float*)d_in[8];
    const float* wo       = (const float*)d_in[9];
    const float* bo       = (const float*)d_in[10];
    const float* ln1_g    = (const float*)d_in[11];
    const float* ln1_b    = (const float*)d_in[12];
    const float* w1       = (const float*)d_in[13];
    const float* b1       = (const float*)d_in[14];
    const float* w2       = (const float*)d_in[15];
    const float* b2       = (const float*)d_in[16];
    const float* ln2_g    = (const float*)d_in[17];
    const float* ln2_b    = (const float*)d_in[18];
    const float* out_w    = (const float*)d_in[19];
    const float* out_b    = (const float*)d_in[20];
    const float* out_ln_g = (const float*)d_in[21];
    const float* out_ln_b = (const float*)d_in[22];

    // ---- workspace carve (bytes) ----
    char* p = (char*)d_ws;
    float* pe   = (float*)p; p += (size_t)S_LEN*HID*4;     // 3.1 MB
    float* z    = (float*)p; p += (size_t)MROWS*EMB*4;     // 2.1 MB
    float* x    = (float*)p; p += (size_t)MROWS*HID*4;     // 12.6 MB
    float* zout = (float*)p; p += (size_t)MROWS*EMB*4;     // 2.1 MB
    u16*  z_b   = (u16*)p;   p += (size_t)MROWS*EMB*2;     // 1.0 MB
    u16*  x_b   = (u16*)p;   p += (size_t)MROWS*HID*2;     // 6.3 MB
    u16*  at_b  = (u16*)p;   p += (size_t)MROWS*HID*2;     // 6.3 MB
    u16*  y_b   = (u16*)p;   p += (size_t)MROWS*HID*2;     // 6.3 MB
    u16*  big   = (u16*)p;   p += (size_t)MROWS*3072*2;    // 25.2 MB
    u16*  wscr  = (u16*)p;   p += (size_t)3072*HID*2;      // 4.7 MB weight scratch
    size_t need = (size_t)(p - (char*)d_ws);
    if (ws_size < need) return;  // loud failure: output stays 0

    hipMemsetAsync(d_out, 0, sizeof(float), stream);

    k_pe<<<(S_LEN*HID+255)/256, 256, 0, stream>>>(pe);
    k_embed_ln<<<MROWS, 64, 0, stream>>>(seq, emb, emb_ln_g, emb_ln_b, z, z_b);

    // x = gelu(z @ proj_w^T + b) + pe   (f32 + bf16)
    k_cvt<<<cvt_grid(HID*EMB), 256, 0, stream>>>(proj_w, wscr, HID*EMB/4);
    k_mm<128,64,2,1,1><<<(768/64)*(MROWS/128), 256, 0, stream>>>(
        z_b, wscr, proj_b, x, x_b, MROWS, HID, EMB, pe);

    for(int l=0; l<LAYERS; ++l){
        k_cvt<<<cvt_grid(2304*HID), 256, 0, stream>>>(wqkv + (size_t)l*2304*HID, wscr, 2304*HID/4);
        k_mm<128,128,0,0,1><<<(2304/128)*(MROWS/128), 256, 0, stream>>>(
            x_b, wscr, bqkv + l*2304, nullptr, big, MROWS, 2304, HID, nullptr);
        k_attn<<<S_LEN*B_DIM*NHEAD, 64, 0, stream>>>(big, at_b);
        k_cvt<<<cvt_grid(HID*HID), 256, 0, stream>>>(wo + (size_t)l*HID*HID, wscr, HID*HID/4);
        k_mm<128,64,0,0,1><<<(768/64)*(MROWS/128), 256, 0, stream>>>(
            at_b, wscr, bo + l*HID, nullptr, y_b, MROWS, HID, HID, nullptr);
        k_add_ln768<<<MROWS, 256, 0, stream>>>(x, x_b, y_b, ln1_g + l*HID, ln1_b + l*HID);
        k_cvt<<<cvt_grid(3072*HID), 256, 0, stream>>>(w1 + (size_t)l*3072*HID, wscr, 3072*HID/4);
        k_mm<128,128,1,0,1><<<(3072/128)*(MROWS/128), 256, 0, stream>>>(
            x_b, wscr, b1 + l*3072, nullptr, big, MROWS, 3072, HID, nullptr);
        k_cvt<<<cvt_grid(3072*HID), 256, 0, stream>>>(w2 + (size_t)l*HID*3072, wscr, 3072*HID/4);
        k_mm<128,64,0,0,1><<<(768/64)*(MROWS/128), 256, 0, stream>>>(
            big, wscr, b2 + l*HID, nullptr, y_b, MROWS, HID, 3072, nullptr);
        k_add_ln768<<<MROWS, 256, 0, stream>>>(x, x_b, y_b, ln2_g + l*HID, ln2_b + l*HID);
    }
    k_cvt<<<cvt_grid(EMB*HID), 256, 0, stream>>>(out_w, wscr, EMB*HID/4);
    k_mm<64,64,0,1,0><<<(EMB/64)*(MROWS/64), 256, 0, stream>>>(
        x_b, wscr, out_b, zout, nullptr, MROWS, EMB, HID, nullptr);
    k_ln128<<<MROWS, 64, 0, stream>>>(zout, out_ln_g, out_ln_b);
    k_loss<<<T_LEN*B_DIM, 64, 0, stream>>>(zout, z, neg_ids, emb,
                                           emb_ln_g, emb_ln_b, (float*)d_out);
}

// Round 5
// 760.249 us; speedup vs baseline: 6.4937x; 1.2527x over previous
//
#include <hip/hip_runtime.h>
#include <hip/hip_bf16.h>
#include <math.h>

#define S_LEN 1024
#define B_DIM 4
#define EMB 128
#define HID 768
#define LAYERS 4
#define CW 3
#define NHEAD 12
#define HDIM 64
#define T_LEN (S_LEN - 4*CW)   // 1012
#define LN_EPS 1e-5f
#define MROWS (S_LEN*B_DIM)    // 4096

typedef unsigned short u16;
typedef __attribute__((ext_vector_type(8))) __bf16 bf16x8;
typedef __attribute__((ext_vector_type(4))) float f32x4;

__device__ __forceinline__ u16 f2b(float f){
    unsigned u = __float_as_uint(f);
    u += 0x7fff + ((u >> 16) & 1);          // round-to-nearest-even
    return (u16)(u >> 16);
}
__device__ __forceinline__ float b2f(u16 h){
    return __uint_as_float(((unsigned)h) << 16);
}
__device__ __forceinline__ float gelu_exact(float x){
    return 0.5f * x * (1.0f + erff(x * 0.70710678118654752f));
}
__device__ __forceinline__ float softplus_f(float x){
    return fmaxf(x, 0.0f) + log1pf(expf(-fabsf(x)));
}
template<int N> __device__ __forceinline__ void waitcnt_vm(){
    if constexpr(N==0) asm volatile("s_waitcnt vmcnt(0)" ::: "memory");
    else if constexpr(N==2) asm volatile("s_waitcnt vmcnt(2)" ::: "memory");
    else if constexpr(N==3) asm volatile("s_waitcnt vmcnt(3)" ::: "memory");
    else if constexpr(N==4) asm volatile("s_waitcnt vmcnt(4)" ::: "memory");
    else if constexpr(N==6) asm volatile("s_waitcnt vmcnt(6)" ::: "memory");
    else if constexpr(N==8) asm volatile("s_waitcnt vmcnt(8)" ::: "memory");
}

// ---------------- f32 -> bf16 weight conversion ----------------
__global__ void k_cvt(const float* __restrict__ w, u16* __restrict__ o, int n4){
    int i = blockIdx.x*256 + threadIdx.x;
    if(i >= n4) return;
    float4 v = *(const float4*)(w + (size_t)i*4);
    ushort4 t; t.x=f2b(v.x); t.y=f2b(v.y); t.z=f2b(v.z); t.w=f2b(v.w);
    *(ushort4*)(o + (size_t)i*4) = t;
}

// ---------------- positional encoding table (S, HID) ----------------
__global__ void k_pe(float* __restrict__ pe){
    int idx = blockIdx.x*256 + threadIdx.x;
    if(idx >= S_LEN*HID) return;
    int s = idx / HID, c = idx % HID;
    int i2 = (c >> 1) * 2;
    float freq = expf(-(float)i2 * (logf(10000.0f) / (float)HID));
    float ang = (float)s * freq;
    pe[idx] = (c & 1) ? cosf(ang) : sinf(ang);
}

// ---------------- z = LN(emb_table[seq^T]) : f32 + bf16 copies ----------------
__global__ void k_embed_ln(const int* __restrict__ seq,
                           const float* __restrict__ emb,
                           const float* __restrict__ g,
                           const float* __restrict__ bta,
                           float* __restrict__ z, u16* __restrict__ zb){
    int row = blockIdx.x;
    int s = row >> 2, b = row & 3;
    int tok = seq[b*S_LEN + s];
    const float* e = emb + (size_t)tok * EMB;
    int lane = threadIdx.x;
    float v0 = e[lane], v1 = e[lane+64];
    float sum = v0+v1, sq = v0*v0+v1*v1;
    #pragma unroll
    for(int off=32; off; off>>=1){ sum += __shfl_xor(sum,off); sq += __shfl_xor(sq,off); }
    float m = sum * (1.0f/128.0f);
    float var = sq*(1.0f/128.0f) - m*m;
    float r = rsqrtf(var + LN_EPS);
    size_t base = (size_t)row*EMB;
    float o0 = (v0-m)*r*g[lane]    + bta[lane];
    float o1 = (v1-m)*r*g[lane+64] + bta[lane+64];
    z[base+lane] = o0; z[base+lane+64] = o1;
    zb[base+lane] = f2b(o0); zb[base+lane+64] = f2b(o1);
}

// ---------------- MFMA GEMM: C[M,N] = A_bf16[M,K] * B_bf16[N,K]^T + bias ----
// BMxBN tile, BK=32, 256 threads (4 waves, 2x2, per-wave BM/2 x BN/2).
// Triple-buffered LDS: tiles t+1,t+2 staged ahead via global_load_lds;
// raw s_barrier + counted s_waitcnt vmcnt(2*IC) -> 2 tiles stay in flight.
// Source chunk pre-swizzled (chunk ^= (row>>1)&3), same XOR on ds_read side.
// EPI: 0 = +bias, 1 = gelu(+bias), 2 = gelu(+bias)+pe. WF/WB: write f32/bf16.
template<int BM, int BN, int EPI, int WF, int WB>
__global__ __launch_bounds__(256) void k_mm(
    const u16*  __restrict__ A,
    const u16*  __restrict__ Bw,
    const float* __restrict__ bias,
    float* __restrict__ Cf, u16* __restrict__ Cb,
    int M, int N, int K, const float* __restrict__ pe)
{
    constexpr int WM = BM/2, WN = BN/2, MR = WM/16, NR = WN/16;
    constexpr int IC = BM/64 + BN/64;       // gload_lds issues per thread/tile
    __shared__ u16 Al[3][BM*32];
    __shared__ u16 Bl[3][BN*32];
    int tid = threadIdx.x;
    int wave = tid >> 6, lane = tid & 63;

    // 1D grid: rows-slow / cols-fast ordering + bijective XCD chunk swizzle
    int nbx = N / BN, nby = M / BM, nwg = nbx * nby;
    int bid = blockIdx.x;
    int q = nwg >> 3, rm = nwg & 7, xcd = bid & 7, off = bid >> 3;
    int sbid = (xcd < rm ? xcd*(q+1) : rm*(q+1) + (xcd-rm)*q) + off;
    int row0 = (sbid / nbx) * BM, col0 = (sbid % nbx) * BN;

    int wr = wave >> 1, wc = wave & 1;
    int lr = lane & 15, lk = lane >> 4;

    f32x4 acc[MR][NR];
    #pragma unroll
    for(int m=0;m<MR;m++)
        #pragma unroll
        for(int n=0;n<NR;n++) acc[m][n] = (f32x4){0.f,0.f,0.f,0.f};

    const char* Abase = (const char*)A;
    const char* Bbase = (const char*)Bw;

    auto stage = [&](int buf, int k0){
        #pragma unroll
        for(int i=0;i<BM/64;i++){
            int p = i*4096 + wave*1024 + lane*16;       // byte offset in tile
            int rr = p >> 6, u = (p >> 4) & 3;
            int us = u ^ ((rr >> 1) & 3);
            const char* g = Abase + ((size_t)(row0+rr)*K + k0)*2 + us*16;
            void* l = (char*)&Al[buf][0] + i*4096 + wave*1024;  // wave-uniform
            __builtin_amdgcn_global_load_lds(
                (const __attribute__((address_space(1))) void*)g,
                (__attribute__((address_space(3))) void*)l, 16, 0, 0);
        }
        #pragma unroll
        for(int i=0;i<BN/64;i++){
            int p = i*4096 + wave*1024 + lane*16;
            int rr = p >> 6, u = (p >> 4) & 3;
            int us = u ^ ((rr >> 1) & 3);
            const char* g = Bbase + ((size_t)(col0+rr)*K + k0)*2 + us*16;
            void* l = (char*)&Bl[buf][0] + i*4096 + wave*1024;
            __builtin_amdgcn_global_load_lds(
                (const __attribute__((address_space(1))) void*)g,
                (__attribute__((address_space(3))) void*)l, 16, 0, 0);
        }
    };

    int nt = K >> 5;
    stage(0, 0);
    if(nt > 1) stage(1, 32);
    int cur = 0;
    for(int t=0; t<nt; ++t){
        int pre = (cur==0) ? 2 : cur-1;     // (t+2)%3
        if(t+2 < nt) stage(pre, (t+2) << 5);
        if(t+2 < nt)      waitcnt_vm<2*IC>();
        else if(t+1 < nt) waitcnt_vm<IC>();
        else              waitcnt_vm<0>();
        __builtin_amdgcn_s_barrier();
        __builtin_amdgcn_sched_barrier(0);
        bf16x8 af[MR], bfr[NR];
        #pragma unroll
        for(int m=0;m<MR;m++){
            int ar = wr*WM + m*16 + lr;
            af[m] = *(const bf16x8*)((const char*)&Al[cur][0] + ar*64 + ((lk ^ ((ar>>1)&3))<<4));
        }
        #pragma unroll
        for(int n=0;n<NR;n++){
            int br = wc*WN + n*16 + lr;
            bfr[n] = *(const bf16x8*)((const char*)&Bl[cur][0] + br*64 + ((lk ^ ((br>>1)&3))<<4));
        }
        #pragma unroll
        for(int m=0;m<MR;m++)
            #pragma unroll
            for(int n=0;n<NR;n++)
                acc[m][n] = __builtin_amdgcn_mfma_f32_16x16x32_bf16(af[m], bfr[n], acc[m][n], 0, 0, 0);
        __builtin_amdgcn_s_barrier();   // all waves done reading buf cur
        cur = (cur==2) ? 0 : cur+1;
    }
    // epilogue: C/D layout col=lane&15, row=(lane>>4)*4+j
    #pragma unroll
    for(int m=0;m<MR;m++){
        #pragma unroll
        for(int n=0;n<NR;n++){
            #pragma unroll
            for(int j=0;j<4;j++){
                int row = row0 + wr*WM + m*16 + lk*4 + j;
                int col = col0 + wc*WN + n*16 + lr;
                float v = acc[m][n][j] + bias[col];
                if(EPI==1) v = gelu_exact(v);
                if(EPI==2) v = gelu_exact(v) + pe[(size_t)(row>>2)*HID + col];
                if(WF) Cf[(size_t)row*N + col] = v;
                if(WB) Cb[(size_t)row*N + col] = f2b(v);
            }
        }
    }
}

// ---------------- banded attention, MFMA QK^T ----------------
// One wave per (16-query tile, b, h). Q,K fragments loaded straight from
// global in MFMA A/B layout. Scores 16x32 via 4 MFMAs; mask+softmax with
// 16-lane-group shfl reductions; normalized P -> LDS [16][36]; PV d-parallel.
__global__ __launch_bounds__(256) void k_attn(const u16* __restrict__ qkv,
                                              u16* __restrict__ out){
    __shared__ float P[4][16][36];
    int wv = threadIdx.x >> 6;
    int lane = threadIdx.x & 63;
    int wid = (blockIdx.x << 2) + wv;      // 0..3071
    int h = wid % NHEAD;
    int b = (wid / NHEAD) & 3;
    int s0 = (wid / (NHEAD*B_DIM)) << 4;   // query tile base
    int lr = lane & 15, lk = lane >> 4;
    const int RS = 3*HID;                  // 2304

    bf16x8 qf[2], kf[2][2];
    #pragma unroll
    for(int kk=0;kk<2;kk++)
        qf[kk] = *(const bf16x8*)(qkv + (size_t)((s0+lr)*B_DIM + b)*RS + h*HDIM + kk*32 + lk*8);
    #pragma unroll
    for(int c=0;c<2;c++){
        int t = s0 + c*16 + lr; if(t > S_LEN-1) t = S_LEN-1;
        #pragma unroll
        for(int kk=0;kk<2;kk++)
            kf[c][kk] = *(const bf16x8*)(qkv + (size_t)(t*B_DIM + b)*RS + HID + h*HDIM + kk*32 + lk*8);
    }
    f32x4 acc0 = {0.f,0.f,0.f,0.f}, acc1 = {0.f,0.f,0.f,0.f};
    #pragma unroll
    for(int kk=0;kk<2;kk++){
        acc0 = __builtin_amdgcn_mfma_f32_16x16x32_bf16(qf[kk], kf[0][kk], acc0, 0,0,0);
        acc1 = __builtin_amdgcn_mfma_f32_16x16x32_bf16(qf[kk], kf[1][kk], acc1, 0,0,0);
    }
    // lane holds key-col = lr, query rows r = 4*lk + j
    float e0[4], e1[4], mx[4], sm[4];
    #pragma unroll
    for(int j=0;j<4;j++){
        int r = 4*lk + j;
        int g0 = lr - r, g1 = 16 + lr - r;
        bool a0 = (g0>=0) & (g0<=12) & (g0!=6);
        bool a1 = (g1>=0) & (g1<=12) & (g1!=6) & (s0+16+lr < S_LEN);
        e0[j] = a0 ? acc0[j]*0.125f : -INFINITY;
        e1[j] = a1 ? acc1[j]*0.125f : -INFINITY;
        mx[j] = fmaxf(e0[j], e1[j]);
    }
    #pragma unroll
    for(int off=1; off<16; off<<=1){
        #pragma unroll
        for(int j=0;j<4;j++) mx[j] = fmaxf(mx[j], __shfl_xor(mx[j], off));
    }
    #pragma unroll
    for(int j=0;j<4;j++){
        e0[j] = expf(e0[j]-mx[j]);
        e1[j] = expf(e1[j]-mx[j]);
        sm[j] = e0[j]+e1[j];
    }
    #pragma unroll
    for(int off=1; off<16; off<<=1){
        #pragma unroll
        for(int j=0;j<4;j++) sm[j] += __shfl_xor(sm[j], off);
    }
    #pragma unroll
    for(int j=0;j<4;j++){
        float inv = 1.0f/sm[j];
        int r = 4*lk + j;
        P[wv][r][lr]      = e0[j]*inv;
        P[wv][r][16+lr]   = e1[j]*inv;
    }
    // PV: lane = d; weights broadcast from LDS (uniform addr), V coalesced
    float o[16];
    #pragma unroll
    for(int r=0;r<16;r++) o[r] = 0.f;
    #pragma unroll
    for(int g4=0; g4<32; g4+=4){
        float vr[4];
        #pragma unroll
        for(int qq=0;qq<4;qq++){
            int t = s0 + g4 + qq; if(t > S_LEN-1) t = S_LEN-1;
            vr[qq] = b2f(qkv[(size_t)(t*B_DIM + b)*RS + 2*HID + h*HDIM + lane]);
        }
        #pragma unroll
        for(int r=0;r<16;r++){
            f32x4 w = *(const f32x4*)&P[wv][r][g4];
            o[r] = fmaf(w[0], vr[0], fmaf(w[1], vr[1], fmaf(w[2], vr[2], fmaf(w[3], vr[3], o[r]))));
        }
    }
    #pragma unroll
    for(int r=0;r<16;r++)
        out[(size_t)((s0+r)*B_DIM + b)*HID + h*HDIM + lane] = f2b(o[r]);
}

// ---------------- x = LN(x + y_b16) over 768; writes f32 x and bf16 xb ------
__global__ __launch_bounds__(256) void k_add_ln768(
    float* __restrict__ x, u16* __restrict__ xb, const u16* __restrict__ y,
    const float* __restrict__ g, const float* __restrict__ bta)
{
    int row = blockIdx.x;
    size_t base = (size_t)row * HID;
    int tid = threadIdx.x;
    float v[3]; float sum=0.f, sq=0.f;
    #pragma unroll
    for(int i=0;i<3;i++){
        int c = tid + i*256;
        float t = x[base+c] + b2f(y[base+c]);
        v[i]=t; sum+=t; sq+=t*t;
    }
    #pragma unroll
    for(int off=32; off; off>>=1){ sum+=__shfl_xor(sum,off); sq+=__shfl_xor(sq,off); }
    __shared__ float s1[4], s2[4];
    int w = tid>>6;
    if((tid&63)==0){ s1[w]=sum; s2[w]=sq; }
    __syncthreads();
    sum = s1[0]+s1[1]+s1[2]+s1[3];
    sq  = s2[0]+s2[1]+s2[2]+s2[3];
    float m = sum*(1.f/768.f);
    float var = sq*(1.f/768.f) - m*m;
    float r = rsqrtf(var+LN_EPS);
    #pragma unroll
    for(int i=0;i<3;i++){
        int c = tid+i*256;
        float o = (v[i]-m)*r*g[c] + bta[c];
        x[base+c] = o;
        xb[base+c] = f2b(o);
    }
}

// ---------------- in-place LN over 128 per row ----------------
__global__ void k_ln128(float* __restrict__ z, const float* __restrict__ g,
                        const float* __restrict__ bta){
    int row = blockIdx.x; int lane = threadIdx.x;
    size_t base = (size_t)row*EMB;
    float v0 = z[base+lane], v1 = z[base+lane+64];
    float sum = v0+v1, sq = v0*v0+v1*v1;
    #pragma unroll
    for(int off=32; off; off>>=1){ sum += __shfl_xor(sum,off); sq += __shfl_xor(sq,off); }
    float m = sum*(1.0f/128.0f);
    float var = sq*(1.0f/128.0f) - m*m;
    float r = rsqrtf(var + LN_EPS);
    z[base+lane]    = (v0-m)*r*g[lane]    + bta[lane];
    z[base+lane+64] = (v1-m)*r*g[lane+64] + bta[lane+64];
}

// ---------------- loss ----------------
__global__ void k_loss(const float* __restrict__ zout, const float* __restrict__ z,
                       const int* __restrict__ neg_ids, const float* __restrict__ emb,
                       const float* __restrict__ g, const float* __restrict__ bta,
                       float* __restrict__ loss)
{
    int bid = blockIdx.x;        // t*B + b
    int t = bid >> 2, b = bid & 3;
    int s = t + CW + 1;
    int lane = threadIdx.x;
    size_t hb = (size_t)(s*B_DIM+b)*EMB;
    float h0 = zout[hb+lane], h1 = zout[hb+lane+64];
    float p = z[hb+lane]*h0 + z[hb+lane+64]*h1;
    int nid = neg_ids[bid];
    const float* e = emb + (size_t)nid*EMB;
    float e0 = e[lane], e1 = e[lane+64];
    float sum = e0+e1, sq = e0*e0+e1*e1;
    #pragma unroll
    for(int off=32; off; off>>=1){
        p   += __shfl_xor(p,off);
        sum += __shfl_xor(sum,off);
        sq  += __shfl_xor(sq,off);
    }
    float m = sum*(1.f/128.f), var = sq*(1.f/128.f)-m*m, r = rsqrtf(var+LN_EPS);
    float zn0 = (e0-m)*r*g[lane]+bta[lane];
    float zn1 = (e1-m)*r*g[lane+64]+bta[lane+64];
    float n = zn0*h0 + zn1*h1;
    #pragma unroll
    for(int off=32; off; off>>=1) n += __shfl_xor(n,off);
    if(lane==0){
        float v = softplus_f(-p) + softplus_f(n);
        atomicAdd(loss, v * (1.0f/(2.0f*T_LEN*B_DIM)));
    }
}

static inline int cvt_grid(int n){ return (n/4 + 255)/256; }

extern "C" void kernel_launch(void* const* d_in, const int* in_sizes, int n_in,
                              void* d_out, int out_size, void* d_ws, size_t ws_size,
                              hipStream_t stream) {
    const int*   seq      = (const int*)  d_in[0];
    const int*   neg_ids  = (const int*)  d_in[1];
    const float* emb      = (const float*)d_in[2];
    const float* emb_ln_g = (const float*)d_in[3];
    const float* emb_ln_b = (const float*)d_in[4];
    const float* proj_w   = (const float*)d_in[5];
    const float* proj_b   = (const float*)d_in[6];
    const float* wqkv     = (const float*)d_in[7];
    const float* bqkv     = (const float*)d_in[8];
    const float* wo       = (const float*)d_in[9];
    const float* bo       = (const float*)d_in[10];
    const float* ln1_g    = (const float*)d_in[11];
    const float* ln1_b    = (const float*)d_in[12];
    const float* w1       = (const float*)d_in[13];
    const float* b1       = (const float*)d_in[14];
    const float* w2       = (const float*)d_in[15];
    const float* b2       = (const float*)d_in[16];
    const float* ln2_g    = (const float*)d_in[17];
    const float* ln2_b    = (const float*)d_in[18];
    const float* out_w    = (const float*)d_in[19];
    const float* out_b    = (const float*)d_in[20];
    const float* out_ln_g = (const float*)d_in[21];
    const float* out_ln_b = (const float*)d_in[22];

    // ---- workspace carve (bytes) ----
    char* p = (char*)d_ws;
    float* pe   = (float*)p; p += (size_t)S_LEN*HID*4;     // 3.1 MB
    float* z    = (float*)p; p += (size_t)MROWS*EMB*4;     // 2.1 MB
    float* x    = (float*)p; p += (size_t)MROWS*HID*4;     // 12.6 MB
    float* zout = (float*)p; p += (size_t)MROWS*EMB*4;     // 2.1 MB
    u16*  z_b   = (u16*)p;   p += (size_t)MROWS*EMB*2;     // 1.0 MB
    u16*  x_b   = (u16*)p;   p += (size_t)MROWS*HID*2;     // 6.3 MB
    u16*  at_b  = (u16*)p;   p += (size_t)MROWS*HID*2;     // 6.3 MB
    u16*  y_b   = (u16*)p;   p += (size_t)MROWS*HID*2;     // 6.3 MB
    u16*  big   = (u16*)p;   p += (size_t)MROWS*3072*2;    // 25.2 MB
    u16*  wscr  = (u16*)p;   p += (size_t)3072*HID*2;      // 4.7 MB weight scratch
    size_t need = (size_t)(p - (char*)d_ws);
    if (ws_size < need) return;  // loud failure: output stays 0

    hipMemsetAsync(d_out, 0, sizeof(float), stream);

    k_pe<<<(S_LEN*HID+255)/256, 256, 0, stream>>>(pe);
    k_embed_ln<<<MROWS, 64, 0, stream>>>(seq, emb, emb_ln_g, emb_ln_b, z, z_b);

    // x = gelu(z @ proj_w^T + b) + pe   (f32 + bf16)
    k_cvt<<<cvt_grid(HID*EMB), 256, 0, stream>>>(proj_w, wscr, HID*EMB/4);
    k_mm<128,64,2,1,1><<<(768/64)*(MROWS/128), 256, 0, stream>>>(
        z_b, wscr, proj_b, x, x_b, MROWS, HID, EMB, pe);

    for(int l=0; l<LAYERS; ++l){
        k_cvt<<<cvt_grid(2304*HID), 256, 0, stream>>>(wqkv + (size_t)l*2304*HID, wscr, 2304*HID/4);
        k_mm<128,128,0,0,1><<<(2304/128)*(MROWS/128), 256, 0, stream>>>(
            x_b, wscr, bqkv + l*2304, nullptr, big, MROWS, 2304, HID, nullptr);
        k_attn<<<(S_LEN/16)*B_DIM*NHEAD/4, 256, 0, stream>>>(big, at_b);
        k_cvt<<<cvt_grid(HID*HID), 256, 0, stream>>>(wo + (size_t)l*HID*HID, wscr, HID*HID/4);
        k_mm<128,64,0,0,1><<<(768/64)*(MROWS/128), 256, 0, stream>>>(
            at_b, wscr, bo + l*HID, nullptr, y_b, MROWS, HID, HID, nullptr);
        k_add_ln768<<<MROWS, 256, 0, stream>>>(x, x_b, y_b, ln1_g + l*HID, ln1_b + l*HID);
        k_cvt<<<cvt_grid(3072*HID), 256, 0, stream>>>(w1 + (size_t)l*3072*HID, wscr, 3072*HID/4);
        k_mm<128,128,1,0,1><<<(3072/128)*(MROWS/128), 256, 0, stream>>>(
            x_b, wscr, b1 + l*3072, nullptr, big, MROWS, 3072, HID, nullptr);
        k_cvt<<<cvt_grid(3072*HID), 256, 0, stream>>>(w2 + (size_t)l*HID*3072, wscr, 3072*HID/4);
        k_mm<128,64,0,0,1><<<(768/64)*(MROWS/128), 256, 0, stream>>>(
            big, wscr, b2 + l*HID, nullptr, y_b, MROWS, HID, 3072, nullptr);
        k_add_ln768<<<MROWS, 256, 0, stream>>>(x, x_b, y_b, ln2_g + l*HID, ln2_b + l*HID);
    }
    k_cvt<<<cvt_grid(EMB*HID), 256, 0, stream>>>(out_w, wscr, EMB*HID/4);
    k_mm<64,64,0,1,0><<<(EMB/64)*(MROWS/64), 256, 0, stream>>>(
        x_b, wscr, out_b, zout, nullptr, MROWS, EMB, HID, nullptr);
    k_ln128<<<MROWS, 64, 0, stream>>>(zout, out_ln_g, out_ln_b);
    k_loss<<<T_LEN*B_DIM, 64, 0, stream>>>(zout, z, neg_ids, emb,
                                           emb_ln_g, emb_ln_b, (float*)d_out);
}